// Round 3
// baseline (146.661 us; speedup 1.0000x reference)
//
#include <hip/hip_runtime.h>
#include <hip/hip_bf16.h>

// Problem constants
#define BPn   2048      // B*P
#define NEn   400
#define RTOT  (BPn*NEn) // 819200
#define TILE_R 64

typedef __attribute__((ext_vector_type(8)))  short  short8;
typedef __attribute__((ext_vector_type(4)))  short  short4v;
typedef __attribute__((ext_vector_type(16))) float  f32x16;
typedef __attribute__((ext_vector_type(4)))  float  f32x4;

__device__ __forceinline__ unsigned short bf16c(float x) {
  return __builtin_bit_cast(unsigned short, __float2bfloat16(x));
}

// x * rcp(1+exp(-x)): 5 VALU ops (2 transcendental). Avoids the IEEE div sequence.
__device__ __forceinline__ float silu_f(float x) {
  return x * __builtin_amdgcn_rcpf(1.0f + __expf(-x));
}

// ---------------- prep: hp[2048][128] and he[400][128] (f32) ----------------
__global__ void prep_emb(const int* __restrict__ z_j, const int* __restrict__ z_k,
                         const float* __restrict__ e_feat, const float* __restrict__ z_emb,
                         const float* __restrict__ W1, const float* __restrict__ b1,
                         float* __restrict__ hp, float* __restrict__ he)
{
  const int t = threadIdx.x;           // 0..127
  const int bidx = blockIdx.x;
  if (bidx < BPn) {
    const int zj = z_j[bidx], zk = z_k[bidx];
    const float* ej = z_emb + zj * 64;
    const float* ek = z_emb + zk * 64;
    float acc = b1[t];
    #pragma unroll 8
    for (int k = 0; k < 64; ++k) acc += ej[k] * W1[k * 128 + t];
    #pragma unroll 8
    for (int k = 0; k < 64; ++k) acc += ek[k] * W1[(64 + k) * 128 + t];
    hp[bidx * 128 + t] = acc;
  } else {
    const int e = bidx - BPn;          // 0..399
    float acc = 0.0f;
    #pragma unroll 8
    for (int k = 0; k < 32; ++k) acc += e_feat[e * 32 + k] * W1[(128 + k) * 128 + t];
    he[e * 128 + t] = acc;
  }
}

// ---------------- prep: weights to bf16 ----------------
// w2cm[n][k] = bf16(W2[k][n])  (col-major, unswizzled, read via L1 in GEMM1)
// w3f layout: [ks][lane][j] with B[k=ks*32+(lane>>4)*8+j][col=lane&15]
__global__ void prep_w(const float* __restrict__ W2, const float* __restrict__ W3,
                       unsigned short* __restrict__ w2cm, unsigned short* __restrict__ w3f)
{
  const int idx = blockIdx.x * 256 + threadIdx.x;
  if (idx < 16384) {
    const int n = idx >> 7, k = idx & 127;
    w2cm[idx] = bf16c(W2[k * 128 + n]);
  }
  if (idx < 2048) {
    const int ks = idx >> 9;
    const int l  = (idx >> 3) & 63;
    const int j  = idx & 7;
    const int k  = ks * 32 + ((l >> 4) & 3) * 8 + j;
    const int col = l & 15;
    w3f[idx] = bf16c(W3[k * 16 + col]);
  }
}

// ---------------- fused main ----------------
// TILE_R=64: LDS 16KB, acc 32 regs -> ~85 total regs -> 6 waves/SIMD target.
__global__ __launch_bounds__(256, 6)
void fused_main(const float* __restrict__ hp, const float* __restrict__ he,
                const unsigned short* __restrict__ w2cm, const unsigned short* __restrict__ w3f,
                const float* __restrict__ b2, const float* __restrict__ b3,
                float* __restrict__ out)
{
  __shared__ __align__(16) unsigned short ldsA[8192]; // 16KB: A (silu layer1), then H2
  const int t    = threadIdx.x;
  const int lane = t & 63;
  const int wid  = t >> 6;
  const int r0   = blockIdx.x * TILE_R;

  // ---- build A = bf16(silu(hp + he)) into ldsA, swizzled [row][k], swz=(row&15)<<4 ----
  {
    const int row0 = t >> 4;              // 0..15 (constant per thread)
    const int k8   = (t & 15) << 3;       // 0,8,...,120 (constant per thread)
    const int swz  = row0 << 4;           // (row&15)<<4 == row0<<4 for all i
    #pragma unroll
    for (int i = 0; i < 4; ++i) {
      const int row = row0 + i * 16;      // 0..63
      const int rg  = r0 + row;
      const unsigned int bp = (unsigned int)(((unsigned long long)rg * 2748779070ull) >> 40); // rg/400 exact
      const unsigned int e  = (unsigned int)rg - bp * 400u;
      const float4* hpv = (const float4*)(hp + bp * 128 + k8);
      const float4* hev = (const float4*)(he + e  * 128 + k8);
      const float4 h0 = hpv[0], h1 = hpv[1];
      const float4 g0 = hev[0], g1 = hev[1];
      float v[8] = { h0.x + g0.x, h0.y + g0.y, h0.z + g0.z, h0.w + g0.w,
                     h1.x + g1.x, h1.y + g1.y, h1.z + g1.z, h1.w + g1.w };
      short8 av;
      #pragma unroll
      for (int j = 0; j < 8; ++j) av[j] = (short)bf16c(silu_f(v[j]));
      *(short8*)((char*)ldsA + ((row * 256 + k8 * 2) ^ swz)) = av;
    }
  }
  __syncthreads();

  // ---- GEMM1: swapped operands -> acc = H2pre^T fragments ----
  // Wave tile: 32 rows x 64 cols. acc[n]: lane&31 = A-row-local, reg = W2-col-local
  const int wm = wid >> 1, wn = wid & 1;   // 2x2 wave grid
  const int c  = lane & 31, hi = lane >> 5;
  f32x16 acc[2] = {};

  const int rowA = wm * 32 + c;
  const int swzA = (c & 15) << 4;          // (rowA&15)<<4 (wm*32 doesn't affect &15)
  const unsigned short* w2p0 = w2cm + (wn * 64 + c) * 128 + hi * 8;
  const unsigned short* w2p1 = w2p0 + 32 * 128;
  #pragma unroll
  for (int ks = 0; ks < 8; ++ks) {
    const int kb2 = (ks * 16 + hi * 8) * 2;
    short8 a0 = *(const short8*)((const char*)ldsA + ((rowA * 256 + kb2) ^ swzA));
    short8 b0 = *(const short8*)(w2p0 + ks * 16);
    short8 b1 = *(const short8*)(w2p1 + ks * 16);
    acc[0] = __builtin_amdgcn_mfma_f32_32x32x16_bf16(b0, a0, acc[0], 0, 0, 0);
    acc[1] = __builtin_amdgcn_mfma_f32_32x32x16_bf16(b1, a0, acc[1], 0, 0, 0);
  }
  __syncthreads();  // everyone done reading ldsA (phase A)

  // ---- bias + silu -> H2 bf16 back into ldsA; lane owns a row, reg-quad = 4 consecutive cols ----
  {
    const int swzH = (c & 15) << 4;        // (rowH&15)<<4
    char* rbase = (char*)ldsA + (wm * 32 + c) * 256;
    #pragma unroll
    for (int n = 0; n < 2; ++n) {
      #pragma unroll
      for (int q = 0; q < 4; ++q) {
        const int colb = wn * 64 + n * 32 + q * 8 + hi * 4;  // cols colb..colb+3
        const float4 bv = *(const float4*)(b2 + colb);
        short4v pk;
        pk[0] = (short)bf16c(silu_f(acc[n][q * 4 + 0] + bv.x));
        pk[1] = (short)bf16c(silu_f(acc[n][q * 4 + 1] + bv.y));
        pk[2] = (short)bf16c(silu_f(acc[n][q * 4 + 2] + bv.z));
        pk[3] = (short)bf16c(silu_f(acc[n][q * 4 + 3] + bv.w));
        *(short4v*)(rbase + ((colb * 2) ^ swzH)) = pk;
      }
    }
  }
  __syncthreads();

  // ---- GEMM2: H2 (64x128) @ W3 (128x16) -> out, 16x16x32 bf16 MFMA ----
  const int l16 = lane & 15, l4 = lane >> 4;
  short8 w3r[4];
  #pragma unroll
  for (int ks = 0; ks < 4; ++ks)
    w3r[ks] = *(const short8*)(w3f + (ks * 64 + lane) * 8);

  const int swz2 = l16 << 4;               // (row&15)<<4 == l16<<4
  const int row2 = wid * 16 + l16;
  f32x4 acc2 = {};
  #pragma unroll
  for (int ks = 0; ks < 4; ++ks) {
    const int kb2 = ks * 64 + l4 * 16;     // byte offset of k-slice
    short8 af = *(const short8*)((const char*)ldsA + ((row2 * 256 + kb2) ^ swz2));
    acc2 = __builtin_amdgcn_mfma_f32_16x16x32_bf16(af, w3r[ks], acc2, 0, 0, 0);
  }

  const float b3v = b3[l16];
  const int rbase = r0 + wid * 16 + l4 * 4;
  #pragma unroll
  for (int j = 0; j < 4; ++j) {
    out[(rbase + j) * 16 + l16] = acc2[j] + b3v;
  }
}

extern "C" void kernel_launch(void* const* d_in, const int* in_sizes, int n_in,
                              void* d_out, int out_size, void* d_ws, size_t ws_size,
                              hipStream_t stream) {
  const int*   z_j    = (const int*)d_in[0];
  const int*   z_k    = (const int*)d_in[1];
  const float* e_feat = (const float*)d_in[2];
  const float* z_emb  = (const float*)d_in[3];
  const float* W1     = (const float*)d_in[4];
  const float* b1     = (const float*)d_in[5];
  const float* W2     = (const float*)d_in[6];
  const float* b2     = (const float*)d_in[7];
  const float* W3     = (const float*)d_in[8];
  const float* b3     = (const float*)d_in[9];
  float* out = (float*)d_out;
  char*  ws  = (char*)d_ws;

  float*          hp   = (float*)(ws);                   // 2048*128*4 = 1 MB
  float*          he   = (float*)(ws + (1 << 20));       // 400*128*4  = 200 KB
  unsigned short* w2cm = (unsigned short*)(ws + 0x140000); // 32 KB
  unsigned short* w3f  = (unsigned short*)(ws + 0x148000); // 4 KB

  hipLaunchKernelGGL(prep_emb, dim3(BPn + NEn), dim3(128), 0, stream,
                     z_j, z_k, e_feat, z_emb, W1, b1, hp, he);
  hipLaunchKernelGGL(prep_w, dim3(64), dim3(256), 0, stream, W2, W3, w2cm, w3f);
  hipLaunchKernelGGL(fused_main, dim3(RTOT / TILE_R), dim3(256), 0, stream,
                     hp, he, w2cm, w3f, b2, b3, out);
}

// Round 4
// 102.095 us; speedup vs baseline: 1.4365x; 1.4365x over previous
//
#include <hip/hip_runtime.h>
#include <hip/hip_bf16.h>

// Problem constants
#define BPn   2048      // B*P
#define NEn   400
#define BT    8         // bp rows per tile
#define ET    8         // e rows per tile
#define TILE_R 64       // BT*ET
#define NT    12800     // (2048/8)*(400/8)
#define GRID  768       // 3 blocks/CU * 256 CU

typedef __attribute__((ext_vector_type(8)))  short  short8;
typedef __attribute__((ext_vector_type(4)))  short  short4v;
typedef __attribute__((ext_vector_type(16))) float  f32x16;
typedef __attribute__((ext_vector_type(4)))  float  f32x4;

__device__ __forceinline__ unsigned short bf16c(float x) {
  return __builtin_bit_cast(unsigned short, __float2bfloat16(x));
}

// x * rcp(1+exp(-x)): avoids the IEEE div sequence.
__device__ __forceinline__ float silu_f(float x) {
  return x * __builtin_amdgcn_rcpf(1.0f + __expf(-x));
}

// ---------------- prep: hp[2048][128] and he[400][128] (f32) ----------------
__global__ void prep_emb(const int* __restrict__ z_j, const int* __restrict__ z_k,
                         const float* __restrict__ e_feat, const float* __restrict__ z_emb,
                         const float* __restrict__ W1, const float* __restrict__ b1,
                         float* __restrict__ hp, float* __restrict__ he)
{
  const int t = threadIdx.x;           // 0..127
  const int bidx = blockIdx.x;
  if (bidx < BPn) {
    const int zj = z_j[bidx], zk = z_k[bidx];
    const float* ej = z_emb + zj * 64;
    const float* ek = z_emb + zk * 64;
    float acc = b1[t];
    #pragma unroll 8
    for (int k = 0; k < 64; ++k) acc += ej[k] * W1[k * 128 + t];
    #pragma unroll 8
    for (int k = 0; k < 64; ++k) acc += ek[k] * W1[(64 + k) * 128 + t];
    hp[bidx * 128 + t] = acc;
  } else {
    const int e = bidx - BPn;          // 0..399
    float acc = 0.0f;
    #pragma unroll 8
    for (int k = 0; k < 32; ++k) acc += e_feat[e * 32 + k] * W1[(128 + k) * 128 + t];
    he[e * 128 + t] = acc;
  }
}

// ---------------- prep: weights to bf16 ----------------
// w2cm[n][k] = bf16(W2[k][n])  (col-major; read once per block into registers)
// w3f layout: [ks][lane][j] with B[k=ks*32+(lane>>4)*8+j][col=lane&15]
__global__ void prep_w(const float* __restrict__ W2, const float* __restrict__ W3,
                       unsigned short* __restrict__ w2cm, unsigned short* __restrict__ w3f)
{
  const int idx = blockIdx.x * 256 + threadIdx.x;
  if (idx < 16384) {
    const int n = idx >> 7, k = idx & 127;
    w2cm[idx] = bf16c(W2[k * 128 + n]);
  }
  if (idx < 2048) {
    const int ks = idx >> 9;
    const int l  = (idx >> 3) & 63;
    const int j  = idx & 7;
    const int k  = ks * 32 + ((l >> 4) & 3) * 8 + j;
    const int col = l & 15;
    w3f[idx] = bf16c(W3[k * 16 + col]);
  }
}

// ---------------- fused main: weights-stationary, 2D (bp,e) tiles ----------------
__global__ __launch_bounds__(256, 3)
void fused_main(const float* __restrict__ hp, const float* __restrict__ he,
                const unsigned short* __restrict__ w2cm, const unsigned short* __restrict__ w3f,
                const float* __restrict__ b2, const float* __restrict__ b3,
                float* __restrict__ out)
{
  __shared__ __align__(16) unsigned short ldsA[8192]; // 16KB: A (silu layer1), then H2
  const int t    = threadIdx.x;
  const int lane = t & 63;
  const int wid  = t >> 6;
  const int wm = wid >> 1, wn = wid & 1;   // 2x2 wave grid; wave tile 32 rows x 64 cols
  const int c  = lane & 31, hi = lane >> 5;

  // ---- per-block hoists (tile-independent) ----
  // W2 fragments in registers: w2r[n][ks], lane c = W2-col (wn*64+n*32+c), hi*8+j = k in ks*16
  short8 w2r[2][8];
  #pragma unroll
  for (int n = 0; n < 2; ++n) {
    const unsigned short* p = w2cm + (wn * 64 + n * 32 + c) * 128 + hi * 8;
    #pragma unroll
    for (int ks = 0; ks < 8; ++ks)
      w2r[n][ks] = *(const short8*)(p + ks * 16);
  }
  // W3 fragments
  short8 w3r[4];
  #pragma unroll
  for (int ks = 0; ks < 4; ++ks)
    w3r[ks] = *(const short8*)(w3f + (ks * 64 + lane) * 8);

  const int l16 = lane & 15, l4 = lane >> 4;
  const float b3v = b3[l16];

  // build-A per-thread constants
  const int row0 = t >> 4;              // 0..15
  const int k8   = (t & 15) << 3;       // 0,8,...,120
  const int swzW = row0 << 4;           // (row&15)<<4 for all build rows
  const int ei0  = row0 & 7;            // e-index constant across i

  for (int tile = blockIdx.x; tile < NT; tile += GRID) {
    const int tbp = (int)(((unsigned)tile * 5243u) >> 18);  // tile/50 exact for tile<12800
    const int te  = tile - tbp * 50;
    const int b0  = tbp * BT;
    const int e0  = te * ET;

    // ---- build A = bf16(silu(hp[bp] + he[e])) into ldsA, swizzled ----
    {
      const float4* hev = (const float4*)(he + (e0 + ei0) * 128 + k8);
      const float4 g0 = hev[0], g1 = hev[1];   // he row: loop-invariant per thread
      #pragma unroll
      for (int i = 0; i < 4; ++i) {
        const int row = row0 + i * 16;         // 0..63
        const int bpi = row >> 3;
        const float4* hpv = (const float4*)(hp + (b0 + bpi) * 128 + k8);
        const float4 h0 = hpv[0], h1 = hpv[1];
        float v[8] = { h0.x + g0.x, h0.y + g0.y, h0.z + g0.z, h0.w + g0.w,
                       h1.x + g1.x, h1.y + g1.y, h1.z + g1.z, h1.w + g1.w };
        short8 av;
        #pragma unroll
        for (int j = 0; j < 8; ++j) av[j] = (short)bf16c(silu_f(v[j]));
        *(short8*)((char*)ldsA + ((row * 256 + k8 * 2) ^ swzW)) = av;
      }
    }
    __syncthreads();

    // ---- GEMM1: acc[n] = H2pre^T fragments; B from registers ----
    f32x16 acc[2] = {};
    {
      const int rowA = wm * 32 + c;
      const int swzA = (c & 15) << 4;
      #pragma unroll
      for (int ks = 0; ks < 8; ++ks) {
        const int kb2 = (ks * 16 + hi * 8) * 2;
        short8 a0 = *(const short8*)((const char*)ldsA + ((rowA * 256 + kb2) ^ swzA));
        acc[0] = __builtin_amdgcn_mfma_f32_32x32x16_bf16(w2r[0][ks], a0, acc[0], 0, 0, 0);
        acc[1] = __builtin_amdgcn_mfma_f32_32x32x16_bf16(w2r[1][ks], a0, acc[1], 0, 0, 0);
      }
    }
    __syncthreads();  // done reading A

    // ---- bias + silu -> H2 bf16 into ldsA; lane owns a row ----
    {
      const int swzH = (c & 15) << 4;
      char* rbase = (char*)ldsA + (wm * 32 + c) * 256;
      #pragma unroll
      for (int n = 0; n < 2; ++n) {
        #pragma unroll
        for (int q = 0; q < 4; ++q) {
          const int colb = wn * 64 + n * 32 + q * 8 + hi * 4;
          const float4 bv = *(const float4*)(b2 + colb);
          short4v pk;
          pk[0] = (short)bf16c(silu_f(acc[n][q * 4 + 0] + bv.x));
          pk[1] = (short)bf16c(silu_f(acc[n][q * 4 + 1] + bv.y));
          pk[2] = (short)bf16c(silu_f(acc[n][q * 4 + 2] + bv.z));
          pk[3] = (short)bf16c(silu_f(acc[n][q * 4 + 3] + bv.w));
          *(short4v*)(rbase + ((colb * 2) ^ swzH)) = pk;
        }
      }
    }
    __syncthreads();

    // ---- GEMM2: H2 (64x128) @ W3 (128x16) ----
    f32x4 acc2 = {};
    {
      const int row2 = wid * 16 + l16;
      const int swz2 = l16 << 4;
      #pragma unroll
      for (int ks = 0; ks < 4; ++ks) {
        const int kb2 = ks * 64 + l4 * 16;
        short8 af = *(const short8*)((const char*)ldsA + ((row2 * 256 + kb2) ^ swz2));
        acc2 = __builtin_amdgcn_mfma_f32_16x16x32_bf16(af, w3r[ks], acc2, 0, 0, 0);
      }
    }

    // ---- store: tile row r -> global row (b0 + r>>3)*400 + (e0 + r&7) ----
    {
      const int obase = (b0 * 400 + e0);
      #pragma unroll
      for (int j = 0; j < 4; ++j) {
        const int r   = wid * 16 + l4 * 4 + j;
        const int rg  = obase + (r >> 3) * 400 + (r & 7);
        out[rg * 16 + l16] = acc2[j] + b3v;
      }
    }
    __syncthreads();  // before next tile overwrites ldsA
  }
}

extern "C" void kernel_launch(void* const* d_in, const int* in_sizes, int n_in,
                              void* d_out, int out_size, void* d_ws, size_t ws_size,
                              hipStream_t stream) {
  const int*   z_j    = (const int*)d_in[0];
  const int*   z_k    = (const int*)d_in[1];
  const float* e_feat = (const float*)d_in[2];
  const float* z_emb  = (const float*)d_in[3];
  const float* W1     = (const float*)d_in[4];
  const float* b1     = (const float*)d_in[5];
  const float* W2     = (const float*)d_in[6];
  const float* b2     = (const float*)d_in[7];
  const float* W3     = (const float*)d_in[8];
  const float* b3     = (const float*)d_in[9];
  float* out = (float*)d_out;
  char*  ws  = (char*)d_ws;

  float*          hp   = (float*)(ws);                     // 2048*128*4 = 1 MB
  float*          he   = (float*)(ws + (1 << 20));         // 400*128*4  = 200 KB
  unsigned short* w2cm = (unsigned short*)(ws + 0x140000); // 32 KB
  unsigned short* w3f  = (unsigned short*)(ws + 0x148000); // 4 KB

  hipLaunchKernelGGL(prep_emb, dim3(BPn + NEn), dim3(128), 0, stream,
                     z_j, z_k, e_feat, z_emb, W1, b1, hp, he);
  hipLaunchKernelGGL(prep_w, dim3(64), dim3(256), 0, stream, W2, W3, w2cm, w3f);
  hipLaunchKernelGGL(fused_main, dim3(GRID), dim3(256), 0, stream,
                     hp, he, w2cm, w3f, b2, b3, out);
}